// Round 12
// baseline (350.915 us; speedup 1.0000x reference)
//
#include <hip/hip_runtime.h>

#define NN 50000
#define EE 800000
#define DD 128
#define CAP 48     // bucket capacity; degrees ~Poisson(16), P(>=48)~6e-11
#define MT 64      // nodes per gemm block
#define XSL 6250   // nodes per XCD slice (NN/8)
#define PB 128     // place blocks per XCD

typedef short short8_t __attribute__((ext_vector_type(8)));
typedef float f32x4 __attribute__((ext_vector_type(4)));

__device__ __forceinline__ unsigned short f2bf(float f) {
    union { float f; unsigned int i; } v; v.f = f;
    unsigned int x = v.i;
    x += 0x7FFFu + ((x >> 16) & 1u);
    return (unsigned short)(x >> 16);
}
__device__ __forceinline__ unsigned int pack2(float a, float b) {
    return (unsigned int)f2bf(a) | ((unsigned int)f2bf(b) << 16);
}
__device__ __forceinline__ float2 bf2x2(unsigned int u) {
    union { unsigned int i; float f; } lo, hi;
    lo.i = u << 16;
    hi.i = u & 0xFFFF0000u;
    return make_float2(lo.f, hi.f);
}

// x -> quarter-major bf16 (xq[q][n][32]); weights -> bf16 (W_fc pre-scaled 0.5).
__global__ void k_conv(const float* __restrict__ x,
                       const float* __restrict__ W_src,
                       const float* __restrict__ W_dst,
                       const float* __restrict__ W_fc,
                       unsigned int* __restrict__ xq,
                       unsigned short* __restrict__ wbf) {
    int t = blockIdx.x * 256 + threadIdx.x;
    int base = t * 4;
    if (base < NN * DD) {
        float4 v = *(const float4*)(x + base);
        int n = base >> 7;
        int c = base & 127;
        int q = c >> 5;
        int w = (c & 31) >> 1;   // uint index within quarter row
        uint2 p; p.x = pack2(v.x, v.y); p.y = pack2(v.z, v.w);
        *(uint2*)(xq + ((size_t)q * NN + n) * 16 + w) = p;
    } else {
        int b2 = base - NN * DD;
        if (b2 < 3 * 16384) {
            int src = b2 >> 14;
            int off = b2 & 16383;
            const float* W = (src == 0) ? W_src : (src == 1) ? W_dst : W_fc;
            float sc = (src == 2) ? 0.5f : 1.0f;
            float4 v = *(const float4*)(W + off);
            uint2 p; p.x = pack2(v.x * sc, v.y * sc); p.y = pack2(v.z * sc, v.w * sc);
            *(uint2*)(wbf + b2) = p;
        }
    }
}

// XCD-sliced bucket fill (round-11, verified win).
__global__ void __launch_bounds__(256) k_place(
    const int* __restrict__ ei, int* __restrict__ cnt,
    unsigned short* __restrict__ bkt_row, unsigned short* __restrict__ bkt_col) {
    int xcd = blockIdx.x & 7;
    int b   = blockIdx.x >> 3;
    int lo = xcd * XSL, hi = lo + XSL;
    for (int e = b * 256 + threadIdx.x; e < EE; e += PB * 256) {
        int r = ei[e];
        int c = ei[EE + e];
        if (r >= lo && r < hi) {
            int po = atomicAdd(&cnt[r], 1);
            if (po < CAP) bkt_row[(size_t)r * CAP + po] = (unsigned short)c;
        }
        if (c >= lo && c < hi) {
            int pi = atomicAdd(&cnt[NN + c], 1);
            if (pi < CAP) bkt_col[(size_t)c * CAP + pi] = (unsigned short)r;
        }
    }
}

__global__ void k_inv(const int* __restrict__ cnt, float* __restrict__ inv) {
    int t = blockIdx.x * 256 + threadIdx.x;
    if (t >= 2 * NN) return;
    int d = cnt[t];
    inv[t] = (d > 0) ? (1.0f / sqrtf((float)d)) : 0.0f;
}

// Quarter-split gather: block = 8 node-teams x 32 lanes, quarter q=blockIdx&3
// (pins each quarter slab to one XCD pair -> L2-resident 3.2MB working set).
// Team: h=lane>>4 picks alternating neighbors, w=lane&15 picks uint (2 bf16).
// Writes oq/iq quarter-major (unscaled) + per-quarter gate logit partials.
__global__ void __launch_bounds__(256) k_gather(
    const unsigned int* __restrict__ xq,
    const unsigned short* __restrict__ bkt_row, const unsigned short* __restrict__ bkt_col,
    const int* __restrict__ cnt,
    const float* __restrict__ o_inv, const float* __restrict__ i_inv,
    const int* __restrict__ in_degree, const int* __restrict__ out_degree,
    const float* __restrict__ W_out_f, const float* __restrict__ W_in_f,
    const float* __restrict__ in_tab, const float* __restrict__ out_tab,
    unsigned int* __restrict__ oq, unsigned int* __restrict__ iq,
    float* __restrict__ logitq)
{
    int b = blockIdx.x;
    int q = b & 3;
    int team = threadIdx.x >> 5;
    int tl = threadIdx.x & 31;
    int h = tl >> 4;
    int w = tl & 15;
    int n = (b >> 2) * 8 + team;          // grid = (NN/8)*4, n always < NN
    const unsigned int* xqq = xq + (size_t)q * NN * 16;
    int f = q * 32 + 2 * w;               // feature index of this lane's pair

    // ---- side 0: out_nei (bkt_row, weight i_inv[nb])
    {
        int deg = cnt[n]; if (deg > CAP) deg = CAP;
        const unsigned short* bp = bkt_row + (size_t)n * CAP;
        float ax = 0.f, ay = 0.f;
        int j = h;
        for (; j + 2 < deg; j += 4) {
            int nb0 = bp[j], nb1 = bp[j + 2];
            float w0 = i_inv[nb0], w1 = i_inv[nb1];
            float2 a = bf2x2(xqq[(size_t)nb0 * 16 + w]);
            float2 c2 = bf2x2(xqq[(size_t)nb1 * 16 + w]);
            ax += w0 * a.x + w1 * c2.x;
            ay += w0 * a.y + w1 * c2.y;
        }
        if (j < deg) {
            int nb = bp[j];
            float w0 = i_inv[nb];
            float2 a = bf2x2(xqq[(size_t)nb * 16 + w]);
            ax += w0 * a.x; ay += w0 * a.y;
        }
        ax += __shfl_xor(ax, 16);
        ay += __shfl_xor(ay, 16);
        float wn = o_inv[n];
        float rx = wn * ax, ry = wn * ay;
        if (h == 0) oq[((size_t)q * NN + n) * 16 + w] = pack2(rx, ry);
        int odg = out_degree[n];
        odg = (odg < 0) ? 0 : (odg > 63 ? 63 : odg);
        float2 xv = bf2x2(xqq[(size_t)n * 16 + w]);
        float2 tb = *(const float2*)(out_tab + (size_t)odg * DD + f);
        float2 wf = *(const float2*)(W_out_f + f);
        float po = (rx - xv.x + tb.x) * wf.x + (ry - xv.y + tb.y) * wf.y;
        po += __shfl_xor(po, 8); po += __shfl_xor(po, 4);
        po += __shfl_xor(po, 2); po += __shfl_xor(po, 1);
        if (tl == 0) logitq[(size_t)q * 2 * NN + 2 * n] = po;
    }

    // ---- side 1: in_nei (bkt_col, weight o_inv[nb])
    {
        int deg = cnt[NN + n]; if (deg > CAP) deg = CAP;
        const unsigned short* bp = bkt_col + (size_t)n * CAP;
        float ax = 0.f, ay = 0.f;
        int j = h;
        for (; j + 2 < deg; j += 4) {
            int nb0 = bp[j], nb1 = bp[j + 2];
            float w0 = o_inv[nb0], w1 = o_inv[nb1];
            float2 a = bf2x2(xqq[(size_t)nb0 * 16 + w]);
            float2 c2 = bf2x2(xqq[(size_t)nb1 * 16 + w]);
            ax += w0 * a.x + w1 * c2.x;
            ay += w0 * a.y + w1 * c2.y;
        }
        if (j < deg) {
            int nb = bp[j];
            float w0 = o_inv[nb];
            float2 a = bf2x2(xqq[(size_t)nb * 16 + w]);
            ax += w0 * a.x; ay += w0 * a.y;
        }
        ax += __shfl_xor(ax, 16);
        ay += __shfl_xor(ay, 16);
        float wn = i_inv[n];
        float rx = wn * ax, ry = wn * ay;
        if (h == 0) iq[((size_t)q * NN + n) * 16 + w] = pack2(rx, ry);
        int idg = in_degree[n];
        idg = (idg < 0) ? 0 : (idg > 63 ? 63 : idg);
        float2 xv = bf2x2(xqq[(size_t)n * 16 + w]);
        float2 tb = *(const float2*)(in_tab + (size_t)idg * DD + f);
        float2 wf = *(const float2*)(W_in_f + f);
        float pi = (rx - xv.x + tb.x) * wf.x + (ry - xv.y + tb.y) * wf.y;
        pi += __shfl_xor(pi, 8); pi += __shfl_xor(pi, 4);
        pi += __shfl_xor(pi, 2); pi += __shfl_xor(pi, 1);
        if (tl == 0) logitq[(size_t)q * 2 * NN + 2 * n + 1] = pi;
    }
}

// Gate: sum quarter logits -> softmax -> masks; pre-scale oq/iq rows in place.
// Block = 4 nodes x 64 lanes (lane = uint index over the 128-bf16 row).
__global__ void __launch_bounds__(256) k_gate(
    const float* __restrict__ logitq,
    const float* __restrict__ odm, const float* __restrict__ odmb,
    const float* __restrict__ idm, const float* __restrict__ idmb,
    const float* __restrict__ b_out_f, const float* __restrict__ b_in_f,
    unsigned int* __restrict__ oq, unsigned int* __restrict__ iq,
    float* __restrict__ scbuf,
    float* __restrict__ outCin, float* __restrict__ outCout)
{
    int n = blockIdx.x * 4 + (threadIdx.x >> 6);
    int l = threadIdx.x & 63;
    if (n >= NN) return;
    float c_out = logitq[2 * n] + logitq[2 * NN + 2 * n]
                + logitq[4 * NN + 2 * n] + logitq[6 * NN + 2 * n] + b_out_f[0];
    float c_in  = logitq[2 * n + 1] + logitq[2 * NN + 2 * n + 1]
                + logitq[4 * NN + 2 * n + 1] + logitq[6 * NN + 2 * n + 1] + b_in_f[0];
    float m  = fmaxf(c_out, c_in);
    float eo = expf(c_out - m);
    float e2 = expf(c_in  - m);
    float inv = 1.0f / (eo + e2);
    float Cout = (eo * inv) * odm[n] + odmb[n];
    float Cin  = (e2 * inv) * idm[n] + idmb[n];
    if (l == 0) {
        scbuf[2 * n] = Cout; scbuf[2 * n + 1] = Cin;
        outCin[n] = Cin; outCout[n] = Cout;
    }
    int q = l >> 4, w = l & 15;
    size_t idx = ((size_t)q * NN + n) * 16 + w;
    unsigned int u = oq[idx];
    float2 a = bf2x2(u);
    oq[idx] = pack2(a.x * Cout, a.y * Cout);
    u = iq[idx];
    a = bf2x2(u);
    iq[idx] = pack2(a.x * Cin, a.y * Cin);
}

// MFMA bf16 GEMM. A-sources quarter-major, PRE-SCALED (staging = pure copy).
__global__ void __launch_bounds__(256) k_gemm(
    const unsigned int* __restrict__ xq,
    const unsigned int* __restrict__ oq, const unsigned int* __restrict__ iq,
    const unsigned short* __restrict__ wbf,
    const float* __restrict__ b_src, const float* __restrict__ b_dst,
    const float* __restrict__ b_fc,
    const float* __restrict__ scbuf,
    float* __restrict__ out)
{
    __shared__ unsigned short sA[MT * 72];    // 64 x (64+8) bf16
    __shared__ unsigned short sBt[DD * 72];   // 128 x (64+8) bf16

    int tid = threadIdx.x;
    int wid = tid >> 6;
    int lane = tid & 63;
    int ml = lane & 15;
    int kq = lane >> 4;
    int n0 = blockIdx.x * MT;

    f32x4 accv[8];
    #pragma unroll
    for (int i = 0; i < 8; i++) accv[i] = (f32x4)0.0f;

    const unsigned int* srcs[3] = { oq, iq, xq };

    for (int kt = 0; kt < 6; kt++) {
        int srcsel = kt >> 1;
        int k0 = (kt & 1) * 64;
        const unsigned int* S = srcs[srcsel];

        // Stage A: pure uint4 copies from quarter-major source.
        #pragma unroll
        for (int r = 0; r < 2; r++) {
            int s = tid + 256 * r;
            int row = s >> 3;
            int cg = s & 7;
            int gn = n0 + row;
            uint4 p = make_uint4(0u, 0u, 0u, 0u);
            if (gn < NN) {
                int f = k0 + cg * 8;            // feature start (uint4 = 8 bf16, intra-quarter)
                int q = f >> 5;
                int w = (f & 31) >> 1;
                p = *(const uint4*)(S + ((size_t)q * NN + gn) * 16 + w);
            }
            *(uint4*)(sA + row * 72 + cg * 8) = p;
        }
        #pragma unroll
        for (int r = 0; r < 4; r++) {
            int s = tid + 256 * r;
            int row = s >> 3;
            int cg = s & 7;
            uint4 wv = *(const uint4*)(wbf + srcsel * 16384 + row * DD + k0 + cg * 8);
            *(uint4*)(sBt + row * 72 + cg * 8) = wv;
        }
        __syncthreads();

        #pragma unroll
        for (int ks = 0; ks < 64; ks += 32) {
            short8_t a = *(const short8_t*)(sA + (16 * wid + ml) * 72 + ks + kq * 8);
            #pragma unroll
            for (int i = 0; i < 8; i++) {
                short8_t bfr = *(const short8_t*)(sBt + (16 * i + ml) * 72 + ks + kq * 8);
                accv[i] = __builtin_amdgcn_mfma_f32_16x16x32_bf16(a, bfr, accv[i], 0, 0, 0);
            }
        }
        __syncthreads();
    }

    // Epilogue: C/D layout col=lane&15, row=(lane>>4)*4+reg.
    int row_base = n0 + 16 * wid + 4 * kq;
    #pragma unroll
    for (int r = 0; r < 4; r++) {
        int row = row_base + r;
        if (row >= NN) continue;
        float Cout = scbuf[2 * row];
        float Cin  = scbuf[2 * row + 1];
        #pragma unroll
        for (int i = 0; i < 8; i++) {
            int col = 16 * i + ml;
            out[(size_t)row * DD + col] =
                accv[i][r] + Cout * b_src[col] + Cin * b_dst[col] + 0.5f * b_fc[col];
        }
    }
}

extern "C" void kernel_launch(void* const* d_in, const int* in_sizes, int n_in,
                              void* d_out, int out_size, void* d_ws, size_t ws_size,
                              hipStream_t stream) {
    const float* x    = (const float*)d_in[0];
    const int* ei     = (const int*)d_in[1];
    const int* in_degree  = (const int*)d_in[2];
    const int* out_degree = (const int*)d_in[3];
    const float* odm  = (const float*)d_in[4];
    const float* odmb = (const float*)d_in[5];
    const float* idm  = (const float*)d_in[6];
    const float* idmb = (const float*)d_in[7];
    const float* W_src = (const float*)d_in[8];
    const float* b_src = (const float*)d_in[9];
    const float* W_dst = (const float*)d_in[10];
    const float* b_dst = (const float*)d_in[11];
    const float* W_out_f = (const float*)d_in[12];
    const float* b_out_f = (const float*)d_in[13];
    const float* W_in_f  = (const float*)d_in[14];
    const float* b_in_f  = (const float*)d_in[15];
    const float* W_fc    = (const float*)d_in[16];
    const float* b_fc    = (const float*)d_in[17];
    const float* in_tab  = (const float*)d_in[18];
    const float* out_tab = (const float*)d_in[19];

    // WS: [xq N*D u16][oq N*D u16][iq N*D u16][scbuf 2N f32][invb 2N f32]
    //     [wbf 3*16384 u16][cnt 2N i32][logitq 8N f32][bkt_row N*CAP u16][bkt_col N*CAP u16]
    unsigned short* xqh = (unsigned short*)d_ws;
    unsigned short* oqh = xqh + (size_t)NN * DD;
    unsigned short* iqh = oqh + (size_t)NN * DD;
    float* scbuf = (float*)(iqh + (size_t)NN * DD);
    float* invb  = scbuf + 2 * NN;
    unsigned short* wbf = (unsigned short*)(invb + 2 * NN);
    int* cnt     = (int*)(wbf + 3 * 16384);
    float* logitq = (float*)(cnt + 2 * NN);
    unsigned short* bkt_row = (unsigned short*)(logitq + 8 * NN);
    unsigned short* bkt_col = bkt_row + (size_t)NN * CAP;

    hipMemsetAsync(cnt, 0, (size_t)2 * NN * sizeof(int), stream);

    int conv_quads = (NN * DD + 3 * 16384) / 4;
    k_conv<<<(conv_quads + 255) / 256, 256, 0, stream>>>(x, W_src, W_dst, W_fc,
                                                         (unsigned int*)xqh, wbf);
    k_place<<<8 * PB, 256, 0, stream>>>(ei, cnt, bkt_row, bkt_col);
    k_inv<<<(2 * NN + 255) / 256, 256, 0, stream>>>(cnt, invb);

    float* o_inv = invb;
    float* i_inv = invb + NN;
    float* out_p  = (float*)d_out;
    float* cin_p  = out_p + (size_t)NN * DD;
    float* cout_p = cin_p + NN;

    k_gather<<<(NN / 8) * 4, 256, 0, stream>>>((const unsigned int*)xqh,
                                               bkt_row, bkt_col, cnt,
                                               o_inv, i_inv, in_degree, out_degree,
                                               W_out_f, W_in_f, in_tab, out_tab,
                                               (unsigned int*)oqh, (unsigned int*)iqh,
                                               logitq);

    k_gate<<<(NN + 3) / 4, 256, 0, stream>>>(logitq, odm, odmb, idm, idmb,
                                             b_out_f, b_in_f,
                                             (unsigned int*)oqh, (unsigned int*)iqh,
                                             scbuf, cin_p, cout_p);

    k_gemm<<<(NN + MT - 1) / MT, 256, 0, stream>>>(
        (const unsigned int*)xqh, (const unsigned int*)oqh, (const unsigned int*)iqh,
        wbf, b_src, b_dst, b_fc, scbuf, out_p);
}